// Round 13
// baseline (5038.005 us; speedup 1.0000x reference)
//
#include <hip/hip_runtime.h>
#include <math.h>

#define TPB 1024   // 16 waves = 4 waves/SIMD; thread = (freq = tid>>1, half = tid&1)

typedef float v2f __attribute__((ext_vector_type(2)));

// Compiler-generated packed math only — NO hand-written v_pk_* asm (R5/R7).
static __device__ __forceinline__ v2f fma2(v2f a, v2f b, v2f c) {
    return __builtin_elementwise_fma(a, b, c);
}
static __device__ __forceinline__ float rcp_nr(float x) {
    float r = __builtin_amdgcn_rcpf(x);
    return r * fmaf(-x, r, 2.0f);
}
static __device__ __forceinline__ v2f rcp2(v2f x) {
    v2f r;
    r.x = __builtin_amdgcn_rcpf(x.x);
    r.y = __builtin_amdgcn_rcpf(x.y);
    v2f two; two.x = 2.0f; two.y = 2.0f;
    return r * (two - x * r);   // NR: ~0.5 ulp
}

// Six independent 2-lane (same-half pair) reductions, ONE row_shr:2 step.
// In a 4-lane group tids are (f,h0),(f,h1),(f+1,h0),(f+1,h1): the same-half
// neighbor is lane^2, so lane2 = lanes0+2 (h0), lane3 = lanes1+3 (h1).
// Untied (=&v outs, in-place ins) — no copy movs. Input order puts the
// last-computed G2 components at chain positions 5-6 (hazard spacing);
// s_nop 1 covers the entry hazard.
__device__ __forceinline__ void red6_p2(float i0, float i1, float i2,
                                        float i3, float i4, float i5,
                                        float& o0, float& o1, float& o2,
                                        float& o3, float& o4, float& o5) {
    asm("s_nop 1\n\t"
        "v_add_f32 %0, %6, %6   row_shr:2 row_mask:0xf bank_mask:0xf bound_ctrl:0\n\t"
        "v_add_f32 %3, %9, %9   row_shr:2 row_mask:0xf bank_mask:0xf bound_ctrl:0\n\t"
        "v_add_f32 %1, %7, %7   row_shr:2 row_mask:0xf bank_mask:0xf bound_ctrl:0\n\t"
        "v_add_f32 %4, %10, %10 row_shr:2 row_mask:0xf bank_mask:0xf bound_ctrl:0\n\t"
        "v_add_f32 %2, %8, %8   row_shr:2 row_mask:0xf bank_mask:0xf bound_ctrl:0\n\t"
        "v_add_f32 %5, %11, %11 row_shr:2 row_mask:0xf bank_mask:0xf bound_ctrl:0"
        : "=&v"(o0), "=&v"(o1), "=&v"(o2), "=&v"(o3), "=&v"(o4), "=&v"(o5)
        : "v"(i0), "v"(i1), "v"(i2), "v"(i3), "v"(i4), "v"(i5));
}

// 8-lane-group combine for the update stage: lane (t&7)==7 gets the group sum.
__device__ __forceinline__ float red1_g8(float g) {
    asm("s_nop 1\n\t"
        "v_add_f32 %0, %0, %0 row_shr:1 row_mask:0xf bank_mask:0xf bound_ctrl:0\n\t"
        "s_nop 1\n\t"
        "v_add_f32 %0, %0, %0 row_shr:2 row_mask:0xf bank_mask:0xf bound_ctrl:0\n\t"
        "s_nop 1\n\t"
        "v_add_f32 %0, %0, %0 row_shr:4 row_mask:0xf bank_mask:0xf bound_ctrl:0"
        : "+v"(g));
    return g;
}

// coefficient k (0..5 = b0,b1,b2,a0,a1,a2) -> paired column
// [b0 a0 b1 a1 b2 a2]: b0,b1,b2 -> 0,2,4 ; a0,a1,a2 -> 1,3,5
__device__ __forceinline__ int cmap(int k) {
    return (k < 3) ? 2 * k : 2 * k - 5;
}

// GSTRIDE=67 (mod 32 = 3) for the NEW 512-row geometry:
// update-read banks 6*oct+3*h+col distinct per coeff octet (conflict-free);
// backward-write banks 6g+3h+8sl+k: 16 distinct g values per wave.
#define GSTRIDE 67

__global__
__attribute__((amdgpu_flat_work_group_size(TPB, TPB), amdgpu_waves_per_eu(4, 4)))
void sgd_filter(const float* __restrict__ sos_in,
                const float* __restrict__ target,
                float* __restrict__ out) {
    // 16 sections padded to 8 floats, PAIRED: [b0 a0 b1 a1 b2 a2 pad pad]
    __shared__ __align__(16) float sos[16 * 8];
    // 512 partial rows: row = 2*(tid>>2) + half, covering 2 freqs each.
    // Rows with even/odd parity hold sections 0..7 / 8..15 respectively.
    __shared__ __align__(16) float gpart[512][GSTRIDE];

    const int tid  = threadIdx.x;
    const int fr   = tid >> 1;     // frequency 0..511
    const int half = tid & 1;      // section half: 0 -> s0..7, 1 -> s8..15
    const float* secbase = &sos[half * 64];   // 8 sections x 8 floats
    const int wrow = 2 * (tid >> 2) + half;   // my gpart row (if writer)

    if (tid < 96) sos[(tid / 6) * 8 + cmap(tid % 6)] = sos_in[tid];

    // Update identity: 8 threads per coefficient u = tid>>3 (tid<768)
    const int u   = tid >> 3;
    const int oct = tid & 7;
    const int usec  = u / 6;                        // section 0..15
    const int uh    = usec >> 3;                    // row parity
    const int ugcol = (usec & 7) * 8 + cmap(u % 6); // gpart col
    const int uscol = usec * 8 + cmap(u % 6);       // sos col
    const int ubase = 2 * oct + uh;                 // first row
    const bool upd = (tid < 768);
    const bool writer = upd && (oct == 7);
    float myc = 0.0f;
    if (writer) myc = sos_in[u];

    // Per-thread frequency constants
    const float w  = (float)((double)fr * (3.14159265358979323846 / 511.0));
    const float c1 = cosf(w);
    const float s1 = -sinf(w);           // z1 = e^{-jw}
    const float c2 = c1 * c1 - s1 * s1;  // z2 = z1^2
    const float s2 = 2.0f * c1 * s1;
    const float tgt = target[fr];
    const float KC = 40.0f / (512.0f * 2.302585092994046f); // 40/(n*ln10)

    // packed loop-invariant splats
    v2f c1v; c1v.x = c1; c1v.y = c1;
    v2f s1v; s1v.x = s1; s1v.y = s1;
    v2f c2v; c2v.x = c2; c2v.y = c2;
    v2f s2v; s2v.x = s2; s2v.y = s2;

    __syncthreads();

    // 8 sections/thread: 16 named v2f direction pairs = 32 VGPRs.
    v2f tR0, tR1, tR2, tR3, tR4, tR5, tR6, tR7;
    v2f tI0, tI1, tI2, tI3, tI4, tI5, tI6, tI7;

#define SEC_FWD(sl)                                                          \
    {                                                                        \
        const float4 q  = *(const float4*)&secbase[(sl) * 8]; /* b0 a0 b1 a1 */ \
        const v2f   ba2 = *(const v2f*)&secbase[(sl) * 8 + 4]; /* b2 a2 */   \
        v2f ba0; ba0.x = q.x; ba0.y = q.y;                                   \
        v2f ba1; ba1.x = q.z; ba1.y = q.w;                                   \
        const v2f Re = fma2(ba2, c2v, fma2(ba1, c1v, ba0));                  \
        const v2f Im = fma2(ba2, s2v, ba1 * s1v);                            \
        const v2f n  = fma2(Re, Re, Im * Im);                                \
        prod = prod * n;                                                     \
        const v2f inv = rcp2(n);                                             \
        tR##sl = Re * inv;                                                   \
        tI##sl = Im * inv;                                                   \
    }

#define SEC_BWD(sl)                                                          \
    {                                                                        \
        const v2f P  = KK * tR##sl;            /* (g_b0, g_a0) */            \
        const v2f Q  = KK * tI##sl;                                          \
        const v2f G1 = fma2(c1v, P, s1v * Q); /* (g_b1, g_a1) */             \
        const v2f G2 = fma2(c2v, P, s2v * Q); /* (g_b2, g_a2) */             \
        float g0, g1, g2, g3, g4, g5;                                        \
        red6_p2(P.x, G1.x, G2.x, P.y, G1.y, G2.y,                            \
                g0, g1, g2, g3, g4, g5);                                     \
        if (tid & 2) {  /* lanes 2,3 of each quad: same-half pair sums */    \
            float* p = &gpart[wrow][(sl) * 8];                               \
            *(float4*)p       = make_float4(g0, g3, g1, g4);                 \
            *(float2*)(p + 4) = make_float2(g2, g5);                         \
        }                                                                    \
    }

    for (int it = 0; it < 1000; ++it) {
        // ---- forward: partial L over my 8 sections (logs grouped 4x) ----
        float L = 0.0f;
        v2f prod;
        prod.x = 1.0f; prod.y = 1.0f;
        SEC_FWD(0) SEC_FWD(1) SEC_FWD(2) SEC_FWD(3)
        L += __builtin_amdgcn_logf(prod.x) - __builtin_amdgcn_logf(prod.y);
        prod.x = 1.0f; prod.y = 1.0f;
        SEC_FWD(4) SEC_FWD(5) SEC_FWD(6) SEC_FWD(7)
        L += __builtin_amdgcn_logf(prod.x) - __builtin_amdgcn_logf(prod.y);

        // ---- L exchange with the adjacent-lane partner (quad_perm[1,0,3,2]);
        // no barrier, no LDS. L + Lsw is commutative -> bit-identical K.
        const int lsw = __builtin_amdgcn_update_dpp(
            0, __float_as_int(L), 0xB1 /*quad_perm 1,0,3,2*/, 0xF, 0xF, true);
        const float Lt = L + __int_as_float(lsw);

        const float mag   = __builtin_amdgcn_exp2f(0.5f * Lt);
        const float magpe = mag + 1e-8f;
        const float indB  = 6.020599913279624f * __builtin_amdgcn_logf(magpe);
        const float diff  = indB - tgt;
        const float K  = KC * diff * mag * rcp_nr(magpe);
        v2f KK; KK.x = K; KK.y = -K;     // A-side gradient sign folded here

        // ---- backward: scale stored directions, 1-step DPP, store ----
        SEC_BWD(0) SEC_BWD(1) SEC_BWD(2) SEC_BWD(3)
        SEC_BWD(4) SEC_BWD(5) SEC_BWD(6) SEC_BWD(7)
        __syncthreads();

        // ---- update: 8 threads/coeff, 32 rows each in 4 chains, DPP combine ----
        if (upd) {
            float a = 0.0f, b = 0.0f, c = 0.0f, d = 0.0f;
#pragma unroll
            for (int j = 0; j < 8; ++j) {
                a += gpart[ubase + 16 * j +   0][ugcol];
                b += gpart[ubase + 16 * j + 128][ugcol];
                c += gpart[ubase + 16 * j + 256][ugcol];
                d += gpart[ubase + 16 * j + 384][ugcol];
            }
            float g = red1_g8((a + b) + (c + d));
            if (writer) {
                myc = fmaf(-0.1f, g, myc);
                sos[uscol] = myc;
            }
        }
        __syncthreads();
    }

    if (writer) out[u] = myc;
}

extern "C" void kernel_launch(void* const* d_in, const int* in_sizes, int n_in,
                              void* d_out, int out_size, void* d_ws, size_t ws_size,
                              hipStream_t stream) {
    const float* sos_in = (const float*)d_in[0];
    const float* target = (const float*)d_in[1];
    float* outp = (float*)d_out;
    hipLaunchKernelGGL(sgd_filter, dim3(1), dim3(TPB), 0, stream, sos_in, target, outp);
}

// Round 14
// 2981.998 us; speedup vs baseline: 1.6895x; 1.6895x over previous
//
#include <hip/hip_runtime.h>
#include <math.h>

#define TPB 1024   // 16 waves = 4 waves/SIMD; thread = (freq = tid>>1, half = tid&1)

typedef float v2f __attribute__((ext_vector_type(2)));

// Compiler-generated packed math only — NO hand-written v_pk_* asm (R5/R7).
static __device__ __forceinline__ v2f fma2(v2f a, v2f b, v2f c) {
    return __builtin_elementwise_fma(a, b, c);
}
static __device__ __forceinline__ float rcp_nr(float x) {
    float r = __builtin_amdgcn_rcpf(x);
    return r * fmaf(-x, r, 2.0f);
}
static __device__ __forceinline__ v2f rcp2(v2f x) {
    v2f r;
    r.x = __builtin_amdgcn_rcpf(x.x);
    r.y = __builtin_amdgcn_rcpf(x.y);
    v2f two; two.x = 2.0f; two.y = 2.0f;
    return r * (two - x * r);   // NR: ~0.5 ulp
}

// Six independent 4-freq same-half reductions: row_shr:2 (lane^2 partner,
// same half) then row_shr:4. Afterwards lanes with (lane&7)>=6 hold the sum
// over their 8-lane group's 4 freqs for their half, with summation tree
// (f3+f2)+(f1+f0) — bit-identical to R12's shr1+shr2 tree.
// Untied (=&v outs, in-place ins) — no copy movs; s_nop 1 covers entry hazard.
__device__ __forceinline__ void red6_p4(float i0, float i1, float i2,
                                        float i3, float i4, float i5,
                                        float& o0, float& o1, float& o2,
                                        float& o3, float& o4, float& o5) {
    asm("s_nop 1\n\t"
        "v_add_f32 %0, %6, %6   row_shr:2 row_mask:0xf bank_mask:0xf bound_ctrl:0\n\t"
        "v_add_f32 %3, %9, %9   row_shr:2 row_mask:0xf bank_mask:0xf bound_ctrl:0\n\t"
        "v_add_f32 %1, %7, %7   row_shr:2 row_mask:0xf bank_mask:0xf bound_ctrl:0\n\t"
        "v_add_f32 %4, %10, %10 row_shr:2 row_mask:0xf bank_mask:0xf bound_ctrl:0\n\t"
        "v_add_f32 %2, %8, %8   row_shr:2 row_mask:0xf bank_mask:0xf bound_ctrl:0\n\t"
        "v_add_f32 %5, %11, %11 row_shr:2 row_mask:0xf bank_mask:0xf bound_ctrl:0\n\t"
        "v_add_f32 %0, %0, %0 row_shr:4 row_mask:0xf bank_mask:0xf bound_ctrl:0\n\t"
        "v_add_f32 %3, %3, %3 row_shr:4 row_mask:0xf bank_mask:0xf bound_ctrl:0\n\t"
        "v_add_f32 %1, %1, %1 row_shr:4 row_mask:0xf bank_mask:0xf bound_ctrl:0\n\t"
        "v_add_f32 %4, %4, %4 row_shr:4 row_mask:0xf bank_mask:0xf bound_ctrl:0\n\t"
        "v_add_f32 %2, %2, %2 row_shr:4 row_mask:0xf bank_mask:0xf bound_ctrl:0\n\t"
        "v_add_f32 %5, %5, %5 row_shr:4 row_mask:0xf bank_mask:0xf bound_ctrl:0"
        : "=&v"(o0), "=&v"(o1), "=&v"(o2), "=&v"(o3), "=&v"(o4), "=&v"(o5)
        : "v"(i0), "v"(i1), "v"(i2), "v"(i3), "v"(i4), "v"(i5));
}

// 8-lane-group combine for the update stage: lane (t&7)==7 gets the group sum.
__device__ __forceinline__ float red1_g8(float g) {
    asm("s_nop 1\n\t"
        "v_add_f32 %0, %0, %0 row_shr:1 row_mask:0xf bank_mask:0xf bound_ctrl:0\n\t"
        "s_nop 1\n\t"
        "v_add_f32 %0, %0, %0 row_shr:2 row_mask:0xf bank_mask:0xf bound_ctrl:0\n\t"
        "s_nop 1\n\t"
        "v_add_f32 %0, %0, %0 row_shr:4 row_mask:0xf bank_mask:0xf bound_ctrl:0"
        : "+v"(g));
    return g;
}

// coefficient k (0..5 = b0,b1,b2,a0,a1,a2) -> paired column
// [b0 a0 b1 a1 b2 a2]: b0,b1,b2 -> 0,2,4 ; a0,a1,a2 -> 1,3,5
__device__ __forceinline__ int cmap(int k) {
    return (k < 3) ? 2 * k : 2 * k - 5;
}

// GSTRIDE=68: 68*4=272 B ≡ 0 mod 16 -> every row float4-ALIGNED (R13's
// stride-67 broke this: odd rows 4B-aligned, float4 ops split, 6x conflicts).
// Write banks 4r+8sl+k over 16 consecutive rows: 2-way = free (m136).
#define GSTRIDE 68

__global__
__attribute__((amdgpu_flat_work_group_size(TPB, TPB), amdgpu_waves_per_eu(4, 4)))
void sgd_filter(const float* __restrict__ sos_in,
                const float* __restrict__ target,
                float* __restrict__ out) {
    // 16 sections padded to 8 floats, PAIRED: [b0 a0 b1 a1 b2 a2 pad pad]
    __shared__ __align__(16) float sos[16 * 8];
    // 256 rows: row = 2*(tid>>3) + half, each covering 4 freqs x 8 sections.
    // Row parity = section half (even -> s0..7, odd -> s8..15).
    __shared__ __align__(16) float gpart[256][GSTRIDE];

    const int tid  = threadIdx.x;
    const int fr   = tid >> 1;     // frequency 0..511
    const int half = tid & 1;      // section half: 0 -> s0..7, 1 -> s8..15
    const float* secbase = &sos[half * 64];   // 8 sections x 8 floats
    const int wrow = 2 * (tid >> 3) + half;   // my gpart row (if writer)

    if (tid < 96) sos[(tid / 6) * 8 + cmap(tid % 6)] = sos_in[tid];

    // Update identity: 8 threads per coefficient u = tid>>3 (tid<768)
    const int u   = tid >> 3;
    const int oct = tid & 7;
    const int usec  = u / 6;                        // section 0..15
    const int uh    = usec >> 3;                    // row parity
    const int ugcol = (usec & 7) * 8 + cmap(u % 6); // gpart col
    const int uscol = usec * 8 + cmap(u % 6);       // sos col
    const bool upd = (tid < 768);
    const bool writer = upd && (oct == 7);
    float myc = 0.0f;
    if (writer) myc = sos_in[u];

    // Per-thread frequency constants
    const float w  = (float)((double)fr * (3.14159265358979323846 / 511.0));
    const float c1 = cosf(w);
    const float s1 = -sinf(w);           // z1 = e^{-jw}
    const float c2 = c1 * c1 - s1 * s1;  // z2 = z1^2
    const float s2 = 2.0f * c1 * s1;
    const float tgt = target[fr];
    const float KC = 40.0f / (512.0f * 2.302585092994046f); // 40/(n*ln10)

    // packed loop-invariant splats
    v2f c1v; c1v.x = c1; c1v.y = c1;
    v2f s1v; s1v.x = s1; s1v.y = s1;
    v2f c2v; c2v.x = c2; c2v.y = c2;
    v2f s2v; s2v.x = s2; s2v.y = s2;

    __syncthreads();

    // 8 sections/thread: 16 named v2f direction pairs = 32 VGPRs.
    v2f tR0, tR1, tR2, tR3, tR4, tR5, tR6, tR7;
    v2f tI0, tI1, tI2, tI3, tI4, tI5, tI6, tI7;

#define SEC_FWD(sl)                                                          \
    {                                                                        \
        const float4 q  = *(const float4*)&secbase[(sl) * 8]; /* b0 a0 b1 a1 */ \
        const v2f   ba2 = *(const v2f*)&secbase[(sl) * 8 + 4]; /* b2 a2 */   \
        v2f ba0; ba0.x = q.x; ba0.y = q.y;                                   \
        v2f ba1; ba1.x = q.z; ba1.y = q.w;                                   \
        const v2f Re = fma2(ba2, c2v, fma2(ba1, c1v, ba0));                  \
        const v2f Im = fma2(ba2, s2v, ba1 * s1v);                            \
        const v2f n  = fma2(Re, Re, Im * Im);                                \
        prod = prod * n;                                                     \
        const v2f inv = rcp2(n);                                             \
        tR##sl = Re * inv;                                                   \
        tI##sl = Im * inv;                                                   \
    }

#define SEC_BWD(sl)                                                          \
    {                                                                        \
        const v2f P  = KK * tR##sl;            /* (g_b0, g_a0) */            \
        const v2f Q  = KK * tI##sl;                                          \
        const v2f G1 = fma2(c1v, P, s1v * Q); /* (g_b1, g_a1) */             \
        const v2f G2 = fma2(c2v, P, s2v * Q); /* (g_b2, g_a2) */             \
        float g0, g1, g2, g3, g4, g5;                                        \
        red6_p4(P.x, G1.x, G2.x, P.y, G1.y, G2.y,                            \
                g0, g1, g2, g3, g4, g5);                                     \
        if ((tid & 7) >= 6) { /* lanes 6,7 of each 8-group */                \
            float* p = &gpart[wrow][(sl) * 8];                               \
            *(float4*)p       = make_float4(g0, g3, g1, g4);                 \
            *(float2*)(p + 4) = make_float2(g2, g5);                         \
        }                                                                    \
    }

    for (int it = 0; it < 1000; ++it) {
        // ---- forward: partial L over my 8 sections (logs grouped 4x) ----
        float L = 0.0f;
        v2f prod;
        prod.x = 1.0f; prod.y = 1.0f;
        SEC_FWD(0) SEC_FWD(1) SEC_FWD(2) SEC_FWD(3)
        L += __builtin_amdgcn_logf(prod.x) - __builtin_amdgcn_logf(prod.y);
        prod.x = 1.0f; prod.y = 1.0f;
        SEC_FWD(4) SEC_FWD(5) SEC_FWD(6) SEC_FWD(7)
        L += __builtin_amdgcn_logf(prod.x) - __builtin_amdgcn_logf(prod.y);

        // ---- L exchange with adjacent-lane partner (quad_perm[1,0,3,2]);
        // no barrier, no LDS; L + Lsw commutative -> bit-identical K.
        const int lsw = __builtin_amdgcn_update_dpp(
            0, __float_as_int(L), 0xB1 /*quad_perm 1,0,3,2*/, 0xF, 0xF, true);
        const float Lt = L + __int_as_float(lsw);

        const float mag   = __builtin_amdgcn_exp2f(0.5f * Lt);
        const float magpe = mag + 1e-8f;
        const float indB  = 6.020599913279624f * __builtin_amdgcn_logf(magpe);
        const float diff  = indB - tgt;
        const float K  = KC * diff * mag * rcp_nr(magpe);
        v2f KK; KK.x = K; KK.y = -K;     // A-side gradient sign folded here

        // ---- backward: scale stored directions, 2-step DPP, store ----
        SEC_BWD(0) SEC_BWD(1) SEC_BWD(2) SEC_BWD(3)
        SEC_BWD(4) SEC_BWD(5) SEC_BWD(6) SEC_BWD(7)
        __syncthreads();

        // ---- update: 8 threads/coeff, 16 rows (parity uh) in 2 chains,
        // same freq-group order as R12 -> bit-identical sums ----
        if (upd) {
            float a = 0.0f, b = 0.0f;
#pragma unroll
            for (int j = 0; j < 8; ++j) {
                a += gpart[2 * (oct + 16 * j) + uh][ugcol];
                b += gpart[2 * (oct + 16 * j + 8) + uh][ugcol];
            }
            float g = red1_g8(a + b);
            if (writer) {
                myc = fmaf(-0.1f, g, myc);
                sos[uscol] = myc;
            }
        }
        __syncthreads();
    }

    if (writer) out[u] = myc;
}

extern "C" void kernel_launch(void* const* d_in, const int* in_sizes, int n_in,
                              void* d_out, int out_size, void* d_ws, size_t ws_size,
                              hipStream_t stream) {
    const float* sos_in = (const float*)d_in[0];
    const float* target = (const float*)d_in[1];
    float* outp = (float*)d_out;
    hipLaunchKernelGGL(sgd_filter, dim3(1), dim3(TPB), 0, stream, sos_in, target, outp);
}